// Round 3
// baseline (358.346 us; speedup 1.0000x reference)
//
#include <hip/hip_runtime.h>

#define CC 64
#define NN 262144            // rows = 8 * 32*32*32
#define NELEM 16777216       // 8*64*32*32*32
#define KK 512
#define CHUNK 128            // codes per LDS chunk
#define NCHUNK (KK/CHUNK)

// Replicates the numpy float32 reference EXACTLY:
//   D[n,k] = f32( f32(A_n + B_k) - f32(2 * C_nk) )
// A_n = np.sum(x^2) with numpy pairwise-8 tree; B_k likewise;
// C_nk = sequential FMA chain over c (OpenBLAS sgemm accumulation order).
// argmin = first index of minimum (strict <).

__global__ __launch_bounds__(256) void vq_main(
    const float* __restrict__ in, const float* __restrict__ cb,
    float* __restrict__ out_idx, double* __restrict__ partials)
{
#pragma clang fp contract(off)
    __shared__ float e_s[CHUNK][CC];   // 32 KB
    __shared__ float b_s[CHUNK];       // ||e_k||^2, numpy rounding
    __shared__ double red_s[256];

    const int tid = threadIdx.x;
    const int n = blockIdx.x * 256 + tid;
    const int b = n >> 15, sp = n & 32767;
    const float* xp = in + ((size_t)b << 21) + sp;   // b*64*32768 + sp

    // row channels -> registers (coalesced across lanes for each c)
    float x[CC];
    #pragma unroll
    for (int c = 0; c < CC; ++c) x[c] = xp[(size_t)c << 15];

    // A = np.sum(x**2): squares rounded individually, pairwise-8 tree
    float r[8];
    #pragma unroll
    for (int j = 0; j < 8; ++j) r[j] = x[j] * x[j];
    #pragma unroll
    for (int i = 8; i < CC; i += 8) {
        #pragma unroll
        for (int j = 0; j < 8; ++j) {
            float sq = x[i + j] * x[i + j];
            r[j] = r[j] + sq;
        }
    }
    const float A = ((r[0] + r[1]) + (r[2] + r[3])) + ((r[4] + r[5]) + (r[6] + r[7]));

    float s1 = 3.4e38f;
    int i1 = 0;

    for (int ch = 0; ch < NCHUNK; ++ch) {
        __syncthreads();
        // stage 128 codes x 64 floats = 2048 float4, 8 per thread
        const float4* src = (const float4*)(cb + ch * CHUNK * CC);
        float4* dst = (float4*)&e_s[0][0];
        #pragma unroll
        for (int i = 0; i < 8; ++i) dst[tid + 256 * i] = src[tid + 256 * i];
        __syncthreads();
        if (tid < CHUNK) {
            // B_k = np.sum(e**2): same pairwise-8 tree
            float q[8];
            #pragma unroll
            for (int j = 0; j < 8; ++j) q[j] = e_s[tid][j] * e_s[tid][j];
            #pragma unroll
            for (int i = 8; i < CC; i += 8) {
                #pragma unroll
                for (int j = 0; j < 8; ++j) {
                    float sq = e_s[tid][i + j] * e_s[tid][i + j];
                    q[j] = q[j] + sq;
                }
            }
            b_s[tid] = ((q[0] + q[1]) + (q[2] + q[3])) + ((q[4] + q[5]) + (q[6] + q[7]));
        }
        __syncthreads();

        for (int k = 0; k < CHUNK; ++k) {
            // C = sequential FMA chain in c-order (sgemm accumulation)
            float cacc = 0.f;
            #pragma unroll
            for (int c = 0; c < CC; c += 4) {
                float4 e = *(const float4*)&e_s[k][c];   // wave-uniform -> broadcast
                cacc = __builtin_fmaf(x[c + 0], e.x, cacc);
                cacc = __builtin_fmaf(x[c + 1], e.y, cacc);
                cacc = __builtin_fmaf(x[c + 2], e.z, cacc);
                cacc = __builtin_fmaf(x[c + 3], e.w, cacc);
            }
            const float t1 = A + b_s[k];          // f32 rounding (numpy: A+B)
            const float t2 = 2.0f * cacc;          // exact
            const float D = t1 - t2;               // f32 rounding (numpy: -2C)
            const int kk = ch * CHUNK + k;
            if (D < s1) { s1 = D; i1 = kk; }       // first-min wins
        }
    }

    out_idx[n] = (float)i1;

    // loss partial: D_best == ||x-e_best||^2 up to ~1e-6 (threshold ~0.025)
    red_s[tid] = (double)s1;
    __syncthreads();
    for (int off = 128; off; off >>= 1) {
        if (tid < off) red_s[tid] += red_s[tid + off];
        __syncthreads();
    }
    if (tid == 0) partials[blockIdx.x] = red_s[0];
}

__global__ __launch_bounds__(256) void vq_out(
    const float* __restrict__ cb, const float* __restrict__ out_idx_f,
    float* __restrict__ out_q, float* __restrict__ out_loss,
    const double* __restrict__ partials)
{
    __shared__ double rs[256];
    const int tid = threadIdx.x;
    const int n = blockIdx.x * 256 + tid;
    const int idx = (int)out_idx_f[n];
    const int b = n >> 15, sp = n & 32767;
    float* qp = out_q + ((size_t)b << 21) + sp;
    const float* e = cb + idx * CC;
    #pragma unroll
    for (int c = 0; c < CC; c += 4) {
        float4 ev = *(const float4*)&e[c];
        qp[(size_t)(c + 0) << 15] = ev.x;
        qp[(size_t)(c + 1) << 15] = ev.y;
        qp[(size_t)(c + 2) << 15] = ev.z;
        qp[(size_t)(c + 3) << 15] = ev.w;
    }

    if (blockIdx.x == 0) {
        double s = partials[tid] + partials[tid + 256] + partials[tid + 512] + partials[tid + 768];
        rs[tid] = s;
        __syncthreads();
        for (int off = 128; off; off >>= 1) {
            if (tid < off) rs[tid] += rs[tid + off];
            __syncthreads();
        }
        if (tid == 0) *out_loss = (float)(1.25 * rs[0] / (double)NELEM);
    }
}

extern "C" void kernel_launch(void* const* d_in, const int* in_sizes, int n_in,
                              void* d_out, int out_size, void* d_ws, size_t ws_size,
                              hipStream_t stream) {
    const float* in = (const float*)d_in[0];
    const float* cb = (const float*)d_in[1];
    float* out      = (float*)d_out;
    float* out_q    = out;                    // [8,64,32,32,32] = 16777216 elems
    float* out_loss = out + NELEM;            // scalar
    float* out_idx  = out + NELEM + 1;        // [262144]

    double* partials = (double*)((unsigned char*)d_ws + 64);

    vq_main<<<NN/256, 256, 0, stream>>>(in, cb, out_idx, partials);
    vq_out<<<NN/256, 256, 0, stream>>>(cb, out_idx, out_q, out_loss, partials);
}

// Round 4
// 344.716 us; speedup vs baseline: 1.0395x; 1.0395x over previous
//
#include <hip/hip_runtime.h>

#define CC 64
#define NN 262144            // rows = 8 * 32*32*32
#define NELEM 16777216       // 8*64*32*32*32
#define KK 512
#define CHUNK 128            // codes per LDS chunk
#define NCHUNK (KK/CHUNK)

// Replicates the numpy float32 reference EXACTLY:
//   D[n,k] = f32( f32(A_n + B_k) - f32(2 * C_nk) )
// A_n = np.sum(x^2) with numpy pairwise-8 tree; B_k likewise;
// C_nk = sequential FMA chain over c (sgemm accumulation order).
// argmin = first index of minimum (strict <).

__global__ __launch_bounds__(256, 3) void vq_main(
    const float* __restrict__ in, const float* __restrict__ cb,
    float* __restrict__ out_idx, double* __restrict__ partials)
{
#pragma clang fp contract(off)
    __shared__ float e_s[CHUNK][CC];   // 32 KB
    __shared__ float b_all[KK];        // 2 KB: ||e_k||^2 for all codes
    __shared__ double red_s[256];      // 2 KB

    const int tid = threadIdx.x;
    const int n = blockIdx.x * 256 + tid;
    const int b = n >> 15, sp = n & 32767;
    const float* xp = in + ((size_t)b << 21) + sp;   // b*64*32768 + sp

    // row channels -> registers (coalesced across lanes for each c)
    float x[CC];
    #pragma unroll
    for (int c = 0; c < CC; ++c) x[c] = xp[(size_t)c << 15];

    // A = np.sum(x**2): squares rounded individually, pairwise-8 tree
    float r[8];
    #pragma unroll
    for (int j = 0; j < 8; ++j) r[j] = x[j] * x[j];
    #pragma unroll
    for (int i = 8; i < CC; i += 8) {
        #pragma unroll
        for (int j = 0; j < 8; ++j) {
            float sq = x[i + j] * x[i + j];
            r[j] = r[j] + sq;
        }
    }
    const float A = ((r[0] + r[1]) + (r[2] + r[3])) + ((r[4] + r[5]) + (r[6] + r[7]));

    // B_k for ALL 512 codes once, straight from global (cb is L2-resident).
    // Avoids the 64-way bank-conflicted column reads of e_s entirely.
    #pragma unroll
    for (int kb = 0; kb < 2; ++kb) {
        const int k = tid + kb * 256;
        const float4* ep = (const float4*)(cb + k * CC);
        float q[8];
        {
            float4 v0 = ep[0], v1 = ep[1];
            q[0] = v0.x * v0.x; q[1] = v0.y * v0.y; q[2] = v0.z * v0.z; q[3] = v0.w * v0.w;
            q[4] = v1.x * v1.x; q[5] = v1.y * v1.y; q[6] = v1.z * v1.z; q[7] = v1.w * v1.w;
        }
        #pragma unroll
        for (int i = 1; i < 8; ++i) {
            float4 v0 = ep[2 * i], v1 = ep[2 * i + 1];
            q[0] = q[0] + v0.x * v0.x; q[1] = q[1] + v0.y * v0.y;
            q[2] = q[2] + v0.z * v0.z; q[3] = q[3] + v0.w * v0.w;
            q[4] = q[4] + v1.x * v1.x; q[5] = q[5] + v1.y * v1.y;
            q[6] = q[6] + v1.z * v1.z; q[7] = q[7] + v1.w * v1.w;
        }
        b_all[k] = ((q[0] + q[1]) + (q[2] + q[3])) + ((q[4] + q[5]) + (q[6] + q[7]));
    }

    float s1 = 3.4e38f;
    int i1 = 0;

    for (int ch = 0; ch < NCHUNK; ++ch) {
        __syncthreads();   // also orders b_all on first iteration
        // stage 128 codes x 64 floats = 2048 float4, 8 per thread
        const float4* src = (const float4*)(cb + ch * CHUNK * CC);
        float4* dst = (float4*)&e_s[0][0];
        #pragma unroll
        for (int i = 0; i < 8; ++i) dst[tid + 256 * i] = src[tid + 256 * i];
        __syncthreads();

        #pragma unroll 2
        for (int k = 0; k < CHUNK; ++k) {
            const float* ek = &e_s[k][0];      // wave-uniform base -> ds_read_b128 offset:N
            float cacc = 0.f;
            #pragma unroll
            for (int c = 0; c < CC; c += 4) {
                float4 e = *(const float4*)(ek + c);
                cacc = __builtin_fmaf(x[c + 0], e.x, cacc);
                cacc = __builtin_fmaf(x[c + 1], e.y, cacc);
                cacc = __builtin_fmaf(x[c + 2], e.z, cacc);
                cacc = __builtin_fmaf(x[c + 3], e.w, cacc);
            }
            const int kk = ch * CHUNK + k;
            const float t1 = A + b_all[kk];    // f32 rounding (numpy: A+B)
            const float t2 = 2.0f * cacc;      // exact
            const float D = t1 - t2;           // f32 rounding (numpy: -2C)
            if (D < s1) { s1 = D; i1 = kk; }   // first-min wins
        }
    }

    out_idx[n] = (float)i1;

    // loss partial: D_best == ||x-e_best||^2 up to ~1e-6 (threshold ~0.025)
    red_s[tid] = (double)s1;
    __syncthreads();
    for (int off = 128; off; off >>= 1) {
        if (tid < off) red_s[tid] += red_s[tid + off];
        __syncthreads();
    }
    if (tid == 0) partials[blockIdx.x] = red_s[0];
}

__global__ __launch_bounds__(256) void vq_out(
    const float* __restrict__ cb, const float* __restrict__ out_idx_f,
    float* __restrict__ out_q, float* __restrict__ out_loss,
    const double* __restrict__ partials)
{
    __shared__ double rs[256];
    const int tid = threadIdx.x;
    const int n = blockIdx.x * 256 + tid;
    const int idx = (int)out_idx_f[n];
    const int b = n >> 15, sp = n & 32767;
    float* qp = out_q + ((size_t)b << 21) + sp;
    const float* e = cb + idx * CC;
    #pragma unroll
    for (int c = 0; c < CC; c += 4) {
        float4 ev = *(const float4*)&e[c];
        qp[(size_t)(c + 0) << 15] = ev.x;
        qp[(size_t)(c + 1) << 15] = ev.y;
        qp[(size_t)(c + 2) << 15] = ev.z;
        qp[(size_t)(c + 3) << 15] = ev.w;
    }

    if (blockIdx.x == 0) {
        double s = partials[tid] + partials[tid + 256] + partials[tid + 512] + partials[tid + 768];
        rs[tid] = s;
        __syncthreads();
        for (int off = 128; off; off >>= 1) {
            if (tid < off) rs[tid] += rs[tid + off];
            __syncthreads();
        }
        if (tid == 0) *out_loss = (float)(1.25 * rs[0] / (double)NELEM);
    }
}

extern "C" void kernel_launch(void* const* d_in, const int* in_sizes, int n_in,
                              void* d_out, int out_size, void* d_ws, size_t ws_size,
                              hipStream_t stream) {
    const float* in = (const float*)d_in[0];
    const float* cb = (const float*)d_in[1];
    float* out      = (float*)d_out;
    float* out_q    = out;                    // [8,64,32,32,32] = 16777216 elems
    float* out_loss = out + NELEM;            // scalar
    float* out_idx  = out + NELEM + 1;        // [262144]

    double* partials = (double*)((unsigned char*)d_ws + 64);

    vq_main<<<NN/256, 256, 0, stream>>>(in, cb, out_idx, partials);
    vq_out<<<NN/256, 256, 0, stream>>>(cb, out_idx, out_q, out_loss, partials);
}